// Round 10
// baseline (97.756 us; speedup 1.0000x reference)
//
#include <hip/hip_runtime.h>
#include <math.h>

#define HH 300
#define WW 300
#define CC 4
#define MM 4096
#define KP 640          // padded K (fp8 bytes/row), 2*W=600 -> 640
#define NKC (KP/32)     // 20 k-chunks of 32 B
#define CSTRIDE 384     // per-coil row stride (6*64: every 64-row block coil-pure)
#define MP (CC*CSTRIDE) // 1536
#define NP 8192         // 2*M (real | imag output columns)

typedef __attribute__((ext_vector_type(4))) float f32x4;
typedef __attribute__((ext_vector_type(4))) int int4v;
typedef __attribute__((ext_vector_type(8))) int int8v;

#define TWO_PI 6.283185307179586f

// Chunk-major: elem (row, k) of an R-row matrix at ((k/32)*R + row)*32 + (k%32).

// prep: zero out[0]; build A (MP x KP fp8 e4m3, chunk-major) and B^T (NP x KP,
// chunk-major). Fully-coalesced stores: wave = 8 rows x 8 4-B slots -> every
// store instruction is a contiguous 256-B run.
__global__ __launch_bounds__(256) void prep_kernel(
    const float* __restrict__ img, const float* __restrict__ csm,
    const float* __restrict__ omega, unsigned char* __restrict__ A,
    unsigned char* __restrict__ B, float* __restrict__ out)
{
    const int bid = blockIdx.x;
    const int t   = threadIdx.x;
    if (bid == 0 && t == 0) out[0] = 0.0f;
    const int lane = t & 63;
    const int jj   = lane & 7;          // 4-B slot within 32-B chunk
    const int rl   = lane >> 3;         // row within the wave's 8-row group

    if (bid < 960) {                    // ---- A: 3840 waves (20 chunks x 192) ----
        int gw = (bid * 256 + t) >> 6;
        int kc = gw / 192;
        int row = (gw - kc * 192) * 8 + rl;       // 0..1535
        int k0 = kc * 32 + jj * 4;
        unsigned int word = 0;
        int c = row / CSTRIDE;
        int h = row - c * CSTRIDE;
        if (h < HH) {
            float v[4];
            #pragma unroll
            for (int q = 0; q < 4; ++q) {
                int k = k0 + q;
                float vv = 0.0f;
                if (k < 2 * WW) {
                    int w = (k < WW) ? k : k - WW;
                    float im = img[h * WW + w];
                    const float* cs = csm + (((size_t)c * HH + h) * WW + w) * 2;
                    vv = ((k < WW) ? cs[0] : cs[1]) * im;
                }
                v[q] = vv;
            }
            unsigned int lo = (unsigned int)(ushort)__builtin_amdgcn_cvt_pk_fp8_f32(v[0], v[1], 0, false);
            unsigned int hi = (unsigned int)(ushort)__builtin_amdgcn_cvt_pk_fp8_f32(v[2], v[3], 0, false);
            word = lo | (hi << 16);
        }
        *(unsigned int*)(A + ((size_t)kc * MP + row) * 32 + jj * 4) = word;
    } else {                            // ---- B: 10240 waves (20 chunks x 512) ----
        int gw = ((bid - 960) * 256 + t) >> 6;
        int kc = gw / 512;
        int m  = (gw - kc * 512) * 8 + rl;
        int k0 = kc * 32 + jj * 4;
        float om1 = omega[MM + m];
        float p0[4], p1[4];
        #pragma unroll
        for (int q = 0; q < 4; ++q) {
            int k = k0 + q;
            float a0 = 0.0f, a1 = 0.0f;
            if (k < 2 * WW) {
                int w = (k < WW) ? k : k - WW;
                float s, c;
                __sincosf(TWO_PI * om1 * (float)(w - 150), &s, &c);
                // ez_r = c, ez_i = -s. real row: [ez_r | -ez_i]; imag row: [ez_i | ez_r]
                a0 = (k < WW) ? c : s;
                a1 = (k < WW) ? -s : c;
            }
            p0[q] = a0; p1[q] = a1;
        }
        unsigned int lo0 = (unsigned int)(ushort)__builtin_amdgcn_cvt_pk_fp8_f32(p0[0], p0[1], 0, false);
        unsigned int hi0 = (unsigned int)(ushort)__builtin_amdgcn_cvt_pk_fp8_f32(p0[2], p0[3], 0, false);
        unsigned int lo1 = (unsigned int)(ushort)__builtin_amdgcn_cvt_pk_fp8_f32(p1[0], p1[1], 0, false);
        unsigned int hi1 = (unsigned int)(ushort)__builtin_amdgcn_cvt_pk_fp8_f32(p1[2], p1[3], 0, false);
        *(unsigned int*)(B + ((size_t)kc * NP + m) * 32 + jj * 4)      = lo0 | (hi0 << 16);
        *(unsigned int*)(B + ((size_t)kc * NP + m + MM) * 32 + jj * 4) = lo1 | (hi1 << 16);
    }
}

// Single-wave fp8 MX GEMM: each 64-thread block computes one 64x64 tile,
// barrier-free, LDS-free. Grid (128 cols, 20 row-blocks) = 2560 blocks.
// blockIdx.y in [0,20) maps to physical row-block y + y/5 (skips all-pad
// row-blocks 6c+5). launch_bounds(64,4) targets <=128 VGPRs / 4 waves per SIMD.
__global__ __launch_bounds__(64, 4) void gemm_kernel(
    const unsigned char* __restrict__ A, const unsigned char* __restrict__ B,
    const float* __restrict__ omega, float2* __restrict__ P)
{
    const int ln   = threadIdx.x;       // 0..63
    const int lr   = ln & 15;
    const int lq   = ln >> 4;
    const int y    = blockIdx.y;        // 0..19 compact row-block id
    const int rbp  = y + y / 5;         // physical row-block (skip 6c+5)
    const int row0 = rbp * 64;
    const int col0 = blockIdx.x * 64;

    f32x4 acc[4][4] = {};

    #pragma unroll
    for (int kc = 0; kc < NKC; kc += 4) {   // 5 fully-unrolled K-steps (K=128 each)
        int8v a[4], b[4];
        #pragma unroll
        for (int i = 0; i < 4; ++i) {
            const unsigned char* pA = A + ((size_t)(kc + lq) * MP + row0 + i * 16 + lr) * 32;
            int4v lo = *(const int4v*)pA;
            int4v hi = *(const int4v*)(pA + 16);
            a[i] = __builtin_shufflevector(lo, hi, 0, 1, 2, 3, 4, 5, 6, 7);
        }
        #pragma unroll
        for (int j = 0; j < 4; ++j) {
            const unsigned char* pB = B + ((size_t)(kc + lq) * NP + col0 + j * 16 + lr) * 32;
            int4v lo = *(const int4v*)pB;
            int4v hi = *(const int4v*)(pB + 16);
            b[j] = __builtin_shufflevector(lo, hi, 0, 1, 2, 3, 4, 5, 6, 7);
        }
        #pragma unroll
        for (int i = 0; i < 4; ++i)
            #pragma unroll
            for (int j = 0; j < 4; ++j)
                acc[i][j] = __builtin_amdgcn_mfma_scale_f32_16x16x128_f8f6f4(
                    a[i], b[j], acc[i][j], 0, 0,      // cbsz=0 (fp8), blgp=0 (fp8)
                    0, 0x7f7f7f7f, 0, 0x7f7f7f7f);    // unit E8M0 scales
    }

    // ---- fused stage-2 epilogue: P[y][col] = sum_h acc * ey(m,h) ----
    // Block is coil-pure: h0 = (rbp % 6) * 64; pad rows (h >= 300) have acc = 0.
    const int h0 = (rbp % 6) * 64;

    #pragma unroll
    for (int j = 0; j < 4; ++j) {
        const int col = col0 + j * 16 + lr;
        const int m = col & (MM - 1);
        const float om0 = omega[m];
        float ss, sc;
        __sincosf(TWO_PI * om0, &ss, &sc);
        const float str = sc, sti = -ss;               // step = exp(-2pi i om0)
        float s2r = str * str - sti * sti, s2i = 2.0f * str * sti;
        float s4r = s2r * s2r - s2i * s2i, s4i = 2.0f * s2r * s2i;
        float s8r = s4r * s4r - s4i * s4i, s8i = 2.0f * s4r * s4i;
        float s16r = s8r * s8r - s8i * s8i, s16i = 2.0f * s8r * s8i;

        const int hb0 = h0 + lq * 4;
        float sn, cs;
        __sincosf(TWO_PI * om0 * (float)(hb0 - 150), &sn, &cs);
        float byr = cs, byi = -sn;                     // ey at h = hb0

        float pr = 0.0f, pi = 0.0f;
        #pragma unroll
        for (int i = 0; i < 4; ++i) {
            float er = byr, ei = byi;
            #pragma unroll
            for (int r = 0; r < 4; ++r) {
                const float v = acc[i][j][r];
                pr = fmaf(v, er, pr);
                pi = fmaf(v, ei, pi);
                float nr = er * str - ei * sti;
                ei = er * sti + ei * str;
                er = nr;
            }
            float nbr = byr * s16r - byi * s16i;       // advance base by 16 rows
            byi = byr * s16i + byi * s16r;
            byr = nbr;
        }
        // combine the 4 lq-lanes sharing this column
        pr += __shfl_down(pr, 32); pi += __shfl_down(pi, 32);
        pr += __shfl_down(pr, 16); pi += __shfl_down(pi, 16);
        if (lq == 0)                                   // lanes 0..15: 128-B contiguous
            P[(size_t)y * NP + col] = make_float2(pr, pi);
    }
}

// loss: k[c,m] from 5 row-block partials (compact ids 5c..5c+4).
__global__ __launch_bounds__(64) void loss_kernel(
    const float2* __restrict__ P, const float* __restrict__ kdata,
    const float* __restrict__ omega, float* __restrict__ out)
{
    const int t = blockIdx.x * 64 + threadIdx.x;   // 0..16383
    const int c = t >> 12;
    const int m = t & (MM - 1);

    float kr = 0.0f, ki = 0.0f;
    #pragma unroll
    for (int q = 0; q < 5; ++q) {
        const int y = 5 * c + q;
        float2 p0 = P[(size_t)y * NP + m];           // real-col partial
        float2 p1 = P[(size_t)y * NP + m + MM];      // imag-col partial
        kr += p0.x - p1.y;
        ki += p0.y + p1.x;
    }
    kr *= (1.0f / 300.0f);
    ki *= (1.0f / 300.0f);

    const float om0 = omega[m];
    const float om1 = omega[MM + m];
    const size_t kidx = ((size_t)c * MM + m) * 2;
    const float kdr = kdata[kidx];
    const float kdi = kdata[kidx + 1];
    const float w0 = om0 * TWO_PI, w1 = om1 * TWO_PI;
    const float wg = sqrtf(w0 * w0 + w1 * w1) + 1.0f;
    const float dr = wg * (kr - kdr);
    const float di = wg * (ki - kdi);
    float val = (dr * dr + di * di) * (1.0f / (2.0f * CC * MM));

    #pragma unroll
    for (int off = 32; off > 0; off >>= 1) val += __shfl_down(val, off);
    if (threadIdx.x == 0) atomicAdd(out, val);
}

extern "C" void kernel_launch(void* const* d_in, const int* in_sizes, int n_in,
                              void* d_out, int out_size, void* d_ws, size_t ws_size,
                              hipStream_t stream) {
    const float* img   = (const float*)d_in[0];   // (300,300,1)
    const float* kdata = (const float*)d_in[1];   // (1,4,4096,2)
    const float* omega = (const float*)d_in[2];   // (1,2,4096)
    const float* csm   = (const float*)d_in[4];   // (4,300,300,2)
    float* out = (float*)d_out;

    unsigned char* Aws = (unsigned char*)d_ws;                  // MP*KP  = 0.98 MB
    unsigned char* Bws = (unsigned char*)d_ws + (1u << 20);     // NP*KP  = 5.24 MB
    float2*        Pws = (float2*)((char*)d_ws + (8u << 20));   // 20*NP*8 = 1.31 MB

    prep_kernel<<<960 + 2560, 256, 0, stream>>>(img, csm, omega, Aws, Bws, out);
    gemm_kernel<<<dim3(NP / 64, 20), 64, 0, stream>>>(Aws, Bws, omega, Pws);
    loss_kernel<<<CC * MM / 64, 64, 0, stream>>>(Pws, kdata, omega, out);
}

// Round 11
// 88.813 us; speedup vs baseline: 1.1007x; 1.1007x over previous
//
#include <hip/hip_runtime.h>
#include <math.h>

#define HH 300
#define WW 300
#define CC 4
#define MM 4096
#define KP 640          // padded K (fp8 bytes/row), 2*W=600 -> 640
#define NKG (KP/128)    // 5 k-groups of 128 B
#define CSTRIDE 384     // per-coil row stride (3*128: every 128-row tile coil-pure)
#define MP (CC*CSTRIDE) // 1536
#define NP 8192         // 2*M (real | imag output columns)
#define NRB (MP/128)    // 12 row-blocks
#define BHALF (2621440) // bytes of B's real-row half (256 row16-groups * 5 * 2048)

typedef __attribute__((ext_vector_type(4))) float f32x4;
typedef __attribute__((ext_vector_type(4))) int int4v;
typedef __attribute__((ext_vector_type(8))) int int8v;

#define TWO_PI 6.283185307179586f

// Fragment-contiguous layout: fragment (row16 = row>>4, g = k>>7) occupies 2048 B
// at ((row16*NKG + g) << 11). Within: addr = hf*1024 + chunk*256 + lr*16 + (k&15)
// where hf=(k>>4)&1, chunk=(k>>5)&3, lr=row&15. A wave's dwordx4 fragment load
// (lane ln reads +ln*16) is then 1024 B fully contiguous -> 16 cache lines, 100% used.

// prep: zero out[0]; build A (MP x KP fp8 e4m3) and B^T (NP x KP fp8) in
// fragment-contiguous layout. Stores are perfectly linear (thread gid -> byte 4*gid).
__global__ __launch_bounds__(256) void prep_kernel(
    const float* __restrict__ img, const float* __restrict__ csm,
    const float* __restrict__ omega, unsigned char* __restrict__ A,
    unsigned char* __restrict__ B, float* __restrict__ out)
{
    const int bid = blockIdx.x;
    const int t   = threadIdx.x;
    if (bid == 0 && t == 0) out[0] = 0.0f;

    if (bid < 960) {                    // ---- A: 960 blocks x 1 KB = 983,040 B ----
        const int gid = bid * 256 + t;
        const int L   = gid * 4;
        const int fragidx = L >> 11;
        const int o  = L & 2047;
        const int hf = (o >> 10) & 1;
        const int ch = (o >> 8) & 3;
        const int lr = (o >> 4) & 15;
        const int b0 = o & 15;
        const int row16 = fragidx / NKG;
        const int g     = fragidx - row16 * NKG;
        const int row = row16 * 16 + lr;
        const int k0  = g * 128 + ch * 32 + hf * 16 + b0;
        const int c = row / CSTRIDE;
        const int h = row - c * CSTRIDE;
        unsigned int word = 0;
        if (h < HH) {
            float v[4];
            #pragma unroll
            for (int q = 0; q < 4; ++q) {
                int k = k0 + q;
                float vv = 0.0f;
                if (k < 2 * WW) {
                    int w = (k < WW) ? k : k - WW;
                    float im = img[h * WW + w];
                    const float* cs = csm + (((size_t)c * HH + h) * WW + w) * 2;
                    vv = ((k < WW) ? cs[0] : cs[1]) * im;
                }
                v[q] = vv;
            }
            unsigned int lo = (unsigned int)(ushort)__builtin_amdgcn_cvt_pk_fp8_f32(v[0], v[1], 0, false);
            unsigned int hi = (unsigned int)(ushort)__builtin_amdgcn_cvt_pk_fp8_f32(v[2], v[3], 0, false);
            word = lo | (hi << 16);
        }
        *(unsigned int*)(A + L) = word;
    } else {                            // ---- B: 2560 blocks over the real-row half ----
        const int gid = (bid - 960) * 256 + t;
        const int L   = gid * 4;                  // offset within first half
        const int fragidx = L >> 11;
        const int o  = L & 2047;
        const int hf = (o >> 10) & 1;
        const int ch = (o >> 8) & 3;
        const int lr = (o >> 4) & 15;
        const int b0 = o & 15;
        const int m16 = fragidx / NKG;
        const int g   = fragidx - m16 * NKG;
        const int m  = m16 * 16 + lr;
        const int k0 = g * 128 + ch * 32 + hf * 16 + b0;
        const float om1 = omega[MM + m];
        float p0[4], p1[4];
        #pragma unroll
        for (int q = 0; q < 4; ++q) {
            int k = k0 + q;
            float a0 = 0.0f, a1 = 0.0f;
            if (k < 2 * WW) {
                int w = (k < WW) ? k : k - WW;
                float s, c;
                __sincosf(TWO_PI * om1 * (float)(w - 150), &s, &c);
                // ez_r = c, ez_i = -s. real row: [ez_r | -ez_i]; imag row: [ez_i | ez_r]
                a0 = (k < WW) ? c : s;
                a1 = (k < WW) ? -s : c;
            }
            p0[q] = a0; p1[q] = a1;
        }
        unsigned int lo0 = (unsigned int)(ushort)__builtin_amdgcn_cvt_pk_fp8_f32(p0[0], p0[1], 0, false);
        unsigned int hi0 = (unsigned int)(ushort)__builtin_amdgcn_cvt_pk_fp8_f32(p0[2], p0[3], 0, false);
        unsigned int lo1 = (unsigned int)(ushort)__builtin_amdgcn_cvt_pk_fp8_f32(p1[0], p1[1], 0, false);
        unsigned int hi1 = (unsigned int)(ushort)__builtin_amdgcn_cvt_pk_fp8_f32(p1[2], p1[3], 0, false);
        *(unsigned int*)(B + L)          = lo0 | (hi0 << 16);  // rows m (real cols)
        *(unsigned int*)(B + BHALF + L)  = lo1 | (hi1 << 16);  // rows m+4096 (imag cols)
    }
}

// Barrier-free fp8 MX GEMM (round-7 structure) with fragment-contiguous loads:
// every fragment load instruction is a fully-coalesced 1024-B wave read.
__global__ __launch_bounds__(256) void gemm_kernel(
    const unsigned char* __restrict__ A, const unsigned char* __restrict__ B,
    const float* __restrict__ omega, float2* __restrict__ P)
{
    __shared__ float2 red[128];

    const int t    = threadIdx.x;
    const int wave = t >> 6;
    const int ln   = t & 63;
    const int row0 = blockIdx.y * 128;
    const int col0 = blockIdx.x * 128;
    const int wr = wave >> 1, wc = wave & 1;
    const int lr = ln & 15;
    const int lq = ln >> 4;

    if (t < 128) red[t] = make_float2(0.0f, 0.0f);

    const int fA0 = (row0 >> 4) + wr * 4;   // fragment row16 base
    const int fB0 = (col0 >> 4) + wc * 4;   // fragment col16 base

    f32x4 acc[4][4] = {};

    #pragma unroll
    for (int g = 0; g < NKG; ++g) {         // 5 fully-unrolled K-steps (K=128 each)
        int8v a[4], b[4];
        #pragma unroll
        for (int i = 0; i < 4; ++i) {
            const unsigned char* pA = A + (((size_t)(fA0 + i) * NKG + g) << 11) + ln * 16;
            int4v lo = *(const int4v*)pA;
            int4v hi = *(const int4v*)(pA + 1024);
            a[i] = __builtin_shufflevector(lo, hi, 0, 1, 2, 3, 4, 5, 6, 7);
        }
        #pragma unroll
        for (int j = 0; j < 4; ++j) {
            const unsigned char* pB = B + (((size_t)(fB0 + j) * NKG + g) << 11) + ln * 16;
            int4v lo = *(const int4v*)pB;
            int4v hi = *(const int4v*)(pB + 1024);
            b[j] = __builtin_shufflevector(lo, hi, 0, 1, 2, 3, 4, 5, 6, 7);
        }
        #pragma unroll
        for (int i = 0; i < 4; ++i)
            #pragma unroll
            for (int j = 0; j < 4; ++j)
                acc[i][j] = __builtin_amdgcn_mfma_scale_f32_16x16x128_f8f6f4(
                    a[i], b[j], acc[i][j], 0, 0,      // cbsz=0 (fp8), blgp=0 (fp8)
                    0, 0x7f7f7f7f, 0, 0x7f7f7f7f);    // unit E8M0 scales
    }

    __syncthreads();   // red[] init visible before epilogue atomics

    // ---- fused stage-2 epilogue: P[rb][col] = sum_h acc * ey(m,h) ----
    const int c  = row0 / CSTRIDE;   // block-uniform (CSTRIDE = 3*128)
    const int h0 = row0 - c * CSTRIDE;

    #pragma unroll
    for (int j = 0; j < 4; ++j) {
        const int jcol = wc * 64 + j * 16 + lr;
        const int m = (col0 + jcol) & (MM - 1);
        const float om0 = omega[m];
        float ss, sc;
        __sincosf(TWO_PI * om0, &ss, &sc);
        const float str = sc, sti = -ss;               // step = exp(-2pi i om0)
        float s2r = str * str - sti * sti, s2i = 2.0f * str * sti;
        float s4r = s2r * s2r - s2i * s2i, s4i = 2.0f * s2r * s2i;
        float s8r = s4r * s4r - s4i * s4i, s8i = 2.0f * s4r * s4i;
        float s16r = s8r * s8r - s8i * s8i, s16i = 2.0f * s8r * s8i;

        const int hb0 = h0 + wr * 64 + lq * 4;
        float sn, cs;
        __sincosf(TWO_PI * om0 * (float)(hb0 - 150), &sn, &cs);
        float byr = cs, byi = -sn;                     // ey at h = hb0

        float pr = 0.0f, pi = 0.0f;
        #pragma unroll
        for (int i = 0; i < 4; ++i) {
            float er = byr, ei = byi;
            #pragma unroll
            for (int r = 0; r < 4; ++r) {
                const float v = acc[i][j][r];
                pr = fmaf(v, er, pr);
                pi = fmaf(v, ei, pi);
                float nr = er * str - ei * sti;
                ei = er * sti + ei * str;
                er = nr;
            }
            float nbr = byr * s16r - byi * s16i;       // advance base by 16 rows
            byi = byr * s16i + byi * s16r;
            byr = nbr;
        }
        pr += __shfl_down(pr, 32); pi += __shfl_down(pi, 32);
        pr += __shfl_down(pr, 16); pi += __shfl_down(pi, 16);
        if (lq == 0) {
            atomicAdd(&red[jcol].x, pr);
            atomicAdd(&red[jcol].y, pi);
        }
    }
    __syncthreads();

    if (t < 128) {
        const int rb = row0 >> 7;
        P[(size_t)rb * NP + col0 + t] = red[t];
    }
}

// loss: k[c,m] from 3 row-block partials. 256 blocks x 64 threads (one wave each).
__global__ __launch_bounds__(64) void loss_kernel(
    const float2* __restrict__ P, const float* __restrict__ kdata,
    const float* __restrict__ omega, float* __restrict__ out)
{
    const int t = blockIdx.x * 64 + threadIdx.x;   // 0..16383
    const int c = t >> 12;
    const int m = t & (MM - 1);

    float kr = 0.0f, ki = 0.0f;
    #pragma unroll
    for (int q = 0; q < 3; ++q) {
        const int rb = 3 * c + q;
        float2 p0 = P[(size_t)rb * NP + m];          // real-col partial
        float2 p1 = P[(size_t)rb * NP + m + MM];     // imag-col partial
        kr += p0.x - p1.y;
        ki += p0.y + p1.x;
    }
    kr *= (1.0f / 300.0f);
    ki *= (1.0f / 300.0f);

    const float om0 = omega[m];
    const float om1 = omega[MM + m];
    const size_t kidx = ((size_t)c * MM + m) * 2;
    const float kdr = kdata[kidx];
    const float kdi = kdata[kidx + 1];
    const float w0 = om0 * TWO_PI, w1 = om1 * TWO_PI;
    const float wg = sqrtf(w0 * w0 + w1 * w1) + 1.0f;
    const float dr = wg * (kr - kdr);
    const float di = wg * (ki - kdi);
    float val = (dr * dr + di * di) * (1.0f / (2.0f * CC * MM));

    #pragma unroll
    for (int off = 32; off > 0; off >>= 1) val += __shfl_down(val, off);
    if (threadIdx.x == 0) atomicAdd(out, val);
}

extern "C" void kernel_launch(void* const* d_in, const int* in_sizes, int n_in,
                              void* d_out, int out_size, void* d_ws, size_t ws_size,
                              hipStream_t stream) {
    const float* img   = (const float*)d_in[0];   // (300,300,1)
    const float* kdata = (const float*)d_in[1];   // (1,4,4096,2)
    const float* omega = (const float*)d_in[2];   // (1,2,4096)
    const float* csm   = (const float*)d_in[4];   // (4,300,300,2)
    float* out = (float*)d_out;

    unsigned char* Aws = (unsigned char*)d_ws;                  // MP*KP  = 0.98 MB
    unsigned char* Bws = (unsigned char*)d_ws + (1u << 20);     // NP*KP  = 5.24 MB
    float2*        Pws = (float2*)((char*)d_ws + (8u << 20));   // NRB*NP*8 = 786 KB

    prep_kernel<<<960 + 2560, 256, 0, stream>>>(img, csm, omega, Aws, Bws, out);
    gemm_kernel<<<dim3(NP / 128, MP / 128), 256, 0, stream>>>(Aws, Bws, omega, Pws);
    loss_kernel<<<CC * MM / 64, 64, 0, stream>>>(Pws, kdata, omega, out);
}